// Round 5
// baseline (885.962 us; speedup 1.0000x reference)
//
#include <hip/hip_runtime.h>
#include <hip/hip_fp16.h>

#define NPTS 131072   // B*S = 128*1024
#define DIM  256
#define KTOT 512
#define GAP_T 0.012f

typedef unsigned short u16;
typedef _Float16 half8 __attribute__((ext_vector_type(8)));
typedef float floatx4 __attribute__((ext_vector_type(4)));

// ---------------- ws layout (main path) ----------------
// 0        : c2 double[512]                    (4096)
// 4096     : Ch u16[512*256]                   (262144)
// 266240   : Cl u16[512*256]                   (262144)
// 528384   : idx int[131072]                   (524288)
// 1052672  : pv1 float[4][131072]              (2097152)   | after combine: offsets int[513], cursors int[512]
// 3149824  : pk1 int[4][131072]                (2097152)
// 5246976  : pv2 float[4][131072]              (2097152)   | after combine: plist int[131072]
// 7344128  : sums float[512*256]               (524288)
// 7868416  : counts int[512]                   (2048)
// 7870464  : flagcnt int[16]                   (64)
// 7870528  : flaglist int[131072]              (524288)
#define WS_MAIN_NEED 8394816u

// ---------- c2 in fp64 (shared by both paths) ----------
__global__ __launch_bounds__(64)
void c2_kernel(const float* __restrict__ c, double* __restrict__ c2) {
  int k = blockIdx.x;
  int lane = threadIdx.x;
  const float* row = c + (size_t)k * DIM;
  double s = 0.0;
#pragma unroll
  for (int r = 0; r < DIM / 64; ++r) {
    float v = row[r * 64 + lane];
    s += (double)v * (double)v;
  }
#pragma unroll
  for (int off = 32; off > 0; off >>= 1) s += __shfl_down(s, off);
  if (lane == 0) c2[k] = s;
}

// ---------- pre-split centroids into hi/lo fp16, swizzled chunk layout ----------
__global__ __launch_bounds__(256)
void csplit_kernel(const float* __restrict__ c, u16* __restrict__ Ch, u16* __restrict__ Cl) {
  int id = blockIdx.x * 256 + threadIdx.x;   // 16384 units
  int n = id >> 5;          // 0..511
  int cg = id & 31;         // global 8-chunk 0..31
  int kc = cg >> 3, cc = cg & 7;
  const float* src = c + (size_t)n * DIM + cg * 8;
  half8 hv, lv;
#pragma unroll
  for (int e = 0; e < 8; ++e) {
    float f = src[e];
    _Float16 h = (_Float16)f;
    hv[e] = h;
    lv[e] = (_Float16)(f - (float)h);
  }
  size_t dst = (size_t)n * DIM + kc * 64 + (size_t)(cc ^ (n & 7)) * 8;
  *(half8*)(Ch + dst) = hv;
  *(half8*)(Cl + dst) = lv;
}

// ---------- MFMA split-fp16 GEMM + per-(block,n-tile) top-2 ----------
__device__ __forceinline__ void load_lds16(const void* g, void* l) {
  __builtin_amdgcn_global_load_lds((const __attribute__((address_space(1))) void*)g,
                                   (__attribute__((address_space(3))) void*)l, 16, 0, 0);
}

__global__ __launch_bounds__(256)
void gemm_topk_kernel(const float* __restrict__ x, const u16* __restrict__ Ch,
                      const u16* __restrict__ Cl, const double* __restrict__ c2,
                      float* __restrict__ pv1, int* __restrict__ pk1, float* __restrict__ pv2) {
  __shared__ __align__(16) unsigned char smem[128 * 132 * 4];  // 67.6 KB, reused
  __shared__ float rb_v[128], rb_v2[128];
  __shared__ int rb_k[128];
  u16* Ah = (u16*)smem;            // [128][64]
  u16* Al = Ah + 8192;
  u16* Bh = Al + 8192;
  u16* Bl = Bh + 8192;

  const int tid = threadIdx.x;
  const int bx = blockIdx.x;
  const int nblk = bx & 3, mblk = bx >> 2;   // adjacent blocks share A-tile (L2)
  const int m0 = mblk * 128, n0 = nblk * 128;
  const int w = tid >> 6, lane = tid & 63;
  const int wm = (w & 1) * 64, wn = (w >> 1) * 64;
  const int lm = lane & 15, quad = lane >> 4;

  floatx4 acc[4][4] = {};

  for (int kc = 0; kc < 4; ++kc) {
    const int k0 = kc * 64;
    __syncthreads();
#pragma unroll
    for (int i = 0; i < 4; ++i) {
      int s = i * 256 + tid;
      int row = s >> 3, pos = s & 7;
      size_t go = (size_t)(n0 + row) * DIM + k0 + pos * 8;
      load_lds16(Ch + go, Bh + (size_t)s * 8);
      load_lds16(Cl + go, Bl + (size_t)s * 8);
    }
#pragma unroll
    for (int i = 0; i < 4; ++i) {
      int s = i * 256 + tid;
      int row = s >> 3, kg = s & 7;
      const float4* gx = (const float4*)(x + (size_t)(m0 + row) * DIM + k0 + kg * 8);
      float4 f0 = gx[0], f1 = gx[1];
      float fv[8] = {f0.x, f0.y, f0.z, f0.w, f1.x, f1.y, f1.z, f1.w};
      half8 hv, lv;
#pragma unroll
      for (int e = 0; e < 8; ++e) {
        _Float16 h = (_Float16)fv[e];
        hv[e] = h;
        lv[e] = (_Float16)(fv[e] - (float)h);
      }
      int pos = kg ^ (row & 7);
      *(half8*)(Ah + (size_t)row * 64 + pos * 8) = hv;
      *(half8*)(Al + (size_t)row * 64 + pos * 8) = lv;
    }
    __syncthreads();

#pragma unroll
    for (int s = 0; s < 2; ++s) {
      half8 ah[4], al[4], bh[4], bl[4];
#pragma unroll
      for (int t = 0; t < 4; ++t) {
        int m = wm + t * 16 + lm;
        int pa = ((s * 4 + quad) ^ (m & 7)) * 8;
        ah[t] = *(const half8*)(Ah + (size_t)m * 64 + pa);
        al[t] = *(const half8*)(Al + (size_t)m * 64 + pa);
        int n = wn + t * 16 + lm;
        int pb = ((s * 4 + quad) ^ (n & 7)) * 8;
        bh[t] = *(const half8*)(Bh + (size_t)n * 64 + pb);
        bl[t] = *(const half8*)(Bl + (size_t)n * 64 + pb);
      }
#pragma unroll
      for (int mt = 0; mt < 4; ++mt)
#pragma unroll
        for (int nt = 0; nt < 4; ++nt) {
          acc[mt][nt] = __builtin_amdgcn_mfma_f32_16x16x32_f16(ah[mt], bh[nt], acc[mt][nt], 0, 0, 0);
          acc[mt][nt] = __builtin_amdgcn_mfma_f32_16x16x32_f16(ah[mt], bl[nt], acc[mt][nt], 0, 0, 0);
          acc[mt][nt] = __builtin_amdgcn_mfma_f32_16x16x32_f16(al[mt], bh[nt], acc[mt][nt], 0, 0, 0);
        }
    }
  }

  // ---- epilogue: scores to LDS (stride 132), per-row top-2
  __syncthreads();
  float* sc = (float*)smem;
  float c2f[4];
#pragma unroll
  for (int nt = 0; nt < 4; ++nt) c2f[nt] = (float)c2[n0 + wn + nt * 16 + lm];
#pragma unroll
  for (int mt = 0; mt < 4; ++mt)
#pragma unroll
    for (int nt = 0; nt < 4; ++nt)
#pragma unroll
      for (int r = 0; r < 4; ++r) {
        int m = wm + mt * 16 + quad * 4 + r;
        int n = wn + nt * 16 + lm;
        sc[m * 132 + n] = c2f[nt] - 2.0f * acc[mt][nt][r];
      }
  __syncthreads();

  {
    int r = tid >> 1, h = tid & 1;
    const float4* rowp4 = (const float4*)(sc + r * 132 + h * 64);
    float bv = 1e30f, sv = 1e30f;
    int bk = 0;
#pragma unroll
    for (int j4 = 0; j4 < 16; ++j4) {
      float4 v4 = rowp4[j4];
      float va[4] = {v4.x, v4.y, v4.z, v4.w};
#pragma unroll
      for (int e = 0; e < 4; ++e) {
        float v = va[e];
        if (v < bv) { sv = bv; bv = v; bk = n0 + h * 64 + j4 * 4 + e; }
        else if (v < sv) sv = v;
      }
    }
    if (h == 1) { rb_v[r] = bv; rb_k[r] = bk; rb_v2[r] = sv; }
    __syncthreads();
    if (h == 0) {
      float ov = rb_v[r], ov2 = rb_v2[r];
      int ok = rb_k[r];
      float fbv, fsv; int fbk;
      if (ov < bv) { fbv = ov; fbk = ok; fsv = fminf(bv, ov2); }
      else         { fbv = bv; fbk = bk; fsv = fminf(sv, ov); }  // tie keeps lower k (h=0)
      int m = m0 + r;
      pv1[(size_t)nblk * NPTS + m] = fbv;
      pk1[(size_t)nblk * NPTS + m] = fbk;
      pv2[(size_t)nblk * NPTS + m] = fsv;
    }
  }
}

// ---------- merge 4 n-block partials -> idx + flag near-ties ----------
__global__ __launch_bounds__(256)
void combine_kernel(const float* __restrict__ pv1, const int* __restrict__ pk1,
                    const float* __restrict__ pv2, int* __restrict__ idx,
                    int* __restrict__ flagcnt, int* __restrict__ flaglist) {
  int m = blockIdx.x * 256 + threadIdx.x;
  float bv = 1e30f, sv = 1e30f;
  int bk = 0;
#pragma unroll
  for (int b = 0; b < 4; ++b) {     // ascending b = ascending k: tie keeps lower k
    float v1 = pv1[(size_t)b * NPTS + m];
    int k1 = pk1[(size_t)b * NPTS + m];
    float v2 = pv2[(size_t)b * NPTS + m];
    if (v1 < bv) { sv = fminf(bv, v2); bv = v1; bk = k1; }
    else { sv = fminf(sv, v1); }
  }
  idx[m] = bk;
  if (sv - bv < GAP_T) {
    int p = atomicAdd(flagcnt, 1);
    flaglist[p] = m;
  }
}

// ---------- batched exact re-check of flagged points (r1 numerics, 64 pts/block) ----------
#define MP 64
#define KT 64
#define DT 32
__global__ __launch_bounds__(256, 2)
void refine_batch_kernel(const float* __restrict__ x, const float* __restrict__ c,
                         const double* __restrict__ c2, const int* __restrict__ flagcnt,
                         const int* __restrict__ flaglist, int* __restrict__ idx) {
  __shared__ __align__(16) float xs[DIM * MP];  // 64 KB, [d][p]
  __shared__ __align__(16) float cs[DT * KT];   // 8 KB, [d][k]
  __shared__ int plds[MP];
  const int tid = threadIdx.x;
  int cnt = *(volatile const int*)flagcnt;
  int nbatch = (cnt + MP - 1) / MP;

  for (int b = blockIdx.x; b < nbatch; b += gridDim.x) {
    __syncthreads();   // LDS reuse guard across batches
    int base = b * MP;
    if (tid < MP) {
      int i = base + tid;
      plds[tid] = (i < cnt) ? flaglist[i] : flaglist[base];  // pad = dup (benign)
    }
    __syncthreads();

    // stage x rows transposed (same as r1 assign)
    {
      const int p = tid >> 2;
      const int dg = tid & 3;
      const float4* x4 = (const float4*)(x + (size_t)plds[p] * DIM);
#pragma unroll
      for (int r = 0; r < 16; ++r) {
        int d4 = r * 4 + dg;
        float4 v = x4[d4];
        int dbase = d4 * 4;
        xs[(dbase + 0) * MP + p] = v.x;
        xs[(dbase + 1) * MP + p] = v.y;
        xs[(dbase + 2) * MP + p] = v.z;
        xs[(dbase + 3) * MP + p] = v.w;
      }
    }

    const int tp = tid & 15;
    const int tk = tid >> 4;
    double best[4]; int bestk[4];
#pragma unroll
    for (int i = 0; i < 4; ++i) { best[i] = 1e300; bestk[i] = 0; }

    for (int kc = 0; kc < KTOT / KT; ++kc) {
      const int k0 = kc * KT;
      double dacc[4][4];
#pragma unroll
      for (int i = 0; i < 4; ++i)
#pragma unroll
        for (int j = 0; j < 4; ++j) dacc[i][j] = 0.0;
      for (int dc = 0; dc < DIM / DT; ++dc) {
        __syncthreads();
        {
          const int kl = tid >> 2;
          const int dg = tid & 3;
          const float4* c4 = (const float4*)(c + (size_t)(k0 + kl) * DIM + dc * DT);
#pragma unroll
          for (int h = 0; h < 2; ++h) {
            int dq = h * 4 + dg;
            float4 v = c4[dq];
            int dbase = dq * 4;
            cs[(dbase + 0) * KT + kl] = v.x;
            cs[(dbase + 1) * KT + kl] = v.y;
            cs[(dbase + 2) * KT + kl] = v.z;
            cs[(dbase + 3) * KT + kl] = v.w;
          }
        }
        __syncthreads();
        float acc[4][4];
#pragma unroll
        for (int i = 0; i < 4; ++i)
#pragma unroll
          for (int j = 0; j < 4; ++j) acc[i][j] = 0.0f;
#pragma unroll
        for (int d = 0; d < DT; ++d) {
          float4 xv = ((const float4*)(xs + (size_t)(dc * DT + d) * MP))[tp];
          float4 cv = ((const float4*)(cs + (size_t)d * KT))[tk];
          float xa[4] = {xv.x, xv.y, xv.z, xv.w};
          float ca[4] = {cv.x, cv.y, cv.z, cv.w};
#pragma unroll
          for (int i = 0; i < 4; ++i)
#pragma unroll
            for (int j = 0; j < 4; ++j) acc[i][j] = fmaf(xa[i], ca[j], acc[i][j]);
        }
#pragma unroll
        for (int i = 0; i < 4; ++i)
#pragma unroll
          for (int j = 0; j < 4; ++j) dacc[i][j] += (double)acc[i][j];
      }
#pragma unroll
      for (int j = 0; j < 4; ++j) {
        int k = k0 + tk * 4 + j;
        double c2v = c2[k];
#pragma unroll
        for (int i = 0; i < 4; ++i) {
          double s = c2v - 2.0 * dacc[i][j];
          if (s < best[i]) { best[i] = s; bestk[i] = k; }
        }
      }
    }

    __syncthreads();
    double* redv = (double*)cs;    // 1024 doubles over cs (8 KB exact)
    int* redk = (int*)xs;          // 1024 ints over xs
#pragma unroll
    for (int i = 0; i < 4; ++i) {
      int p = tp * 4 + i;
      redv[tk * MP + p] = best[i];
      redk[tk * MP + p] = bestk[i];
    }
    __syncthreads();
    if (tid < MP) {
      int p = tid;
      double bv = redv[p]; int bkk = redk[p];
#pragma unroll
      for (int t = 1; t < 16; ++t) {
        double v = redv[t * MP + p]; int kk = redk[t * MP + p];
        if (v < bv || (v == bv && kk < bkk)) { bv = v; bkk = kk; }
      }
      if (base + p < cnt) idx[plds[p]] = bkk;
    }
  }
}

// ---------- one-hot write ----------
__global__ __launch_bounds__(256)
void onehot_kernel(const int* __restrict__ idx, float* __restrict__ out) {
  __shared__ int bk[32];
  int b = blockIdx.x;  // 32 points per block
  if (threadIdx.x < 32) bk[threadIdx.x] = idx[b * 32 + threadIdx.x];
  __syncthreads();
  float4* o = (float4*)(out + (size_t)b * 32 * KTOT);
#pragma unroll
  for (int j = 0; j < 16; ++j) {
    int f4 = j * 256 + threadIdx.x;   // 0..4095
    int p = f4 >> 7;                  // 128 float4 per row
    int n4 = (f4 & 127) * 4;
    int k = bk[p];
    float4 v;
    v.x = (k == n4 + 0) ? 1.0f : 0.0f;
    v.y = (k == n4 + 1) ? 1.0f : 0.0f;
    v.z = (k == n4 + 2) ? 1.0f : 0.0f;
    v.w = (k == n4 + 3) ? 1.0f : 0.0f;
    o[f4] = v;
  }
}

// ================= counting-sort sums pipeline =================
__global__ __launch_bounds__(256)
void hist_kernel(const int* __restrict__ idx, int* __restrict__ counts) {
  __shared__ int h[KTOT];
  int t = threadIdx.x;
#pragma unroll
  for (int i = 0; i < KTOT / 256; ++i) h[i * 256 + t] = 0;
  __syncthreads();
  int base = blockIdx.x * 1024 + t;
#pragma unroll
  for (int j = 0; j < 4; ++j) atomicAdd(&h[idx[base + j * 256]], 1);
  __syncthreads();
#pragma unroll
  for (int i = 0; i < KTOT / 256; ++i) {
    int v = h[i * 256 + t];
    if (v) atomicAdd(&counts[i * 256 + t], v);
  }
}

__global__ __launch_bounds__(512)
void scan_kernel(const int* __restrict__ counts, int* __restrict__ offsets,
                 int* __restrict__ cursors) {
  __shared__ int s[KTOT];
  int t = threadIdx.x;
  int mine = counts[t];
  s[t] = mine;
  __syncthreads();
  for (int off = 1; off < KTOT; off <<= 1) {
    int v = (t >= off) ? s[t - off] : 0;
    __syncthreads();
    s[t] += v;
    __syncthreads();
  }
  int excl = s[t] - mine;
  offsets[t] = excl;
  cursors[t] = excl;
  if (t == KTOT - 1) offsets[KTOT] = s[t];
}

__global__ __launch_bounds__(256)
void scatter_kernel(const int* __restrict__ idx, int* __restrict__ cursors,
                    int* __restrict__ plist) {
  int base = blockIdx.x * 1024 + threadIdx.x;
#pragma unroll
  for (int j = 0; j < 4; ++j) {
    int n = base + j * 256;
    int k = idx[n];
    int pos = atomicAdd(&cursors[k], 1);
    plist[pos] = n;
  }
}

// gathersum_flat: skew-proof — every wave owns 32 consecutive sorted positions.
__global__ __launch_bounds__(256)
void gathersum_flat_kernel(const float* __restrict__ x, const int* __restrict__ plist,
                           const int* __restrict__ offsets, float* __restrict__ sums) {
  __shared__ int offs[KTOT + 1];
  for (int t = threadIdx.x; t < KTOT + 1; t += 256) offs[t] = offsets[t];
  __syncthreads();
  const int w = threadIdx.x >> 6, lane = threadIdx.x & 63;
  const int wid = blockIdx.x * 4 + w;   // 4096 waves total
  const int p0 = wid * 32, p1 = p0 + 32;

  int lo = 0, hi = KTOT;
  while (hi - lo > 1) { int mid = (lo + hi) >> 1; if (offs[mid] <= p0) lo = mid; else hi = mid; }
  int k = lo;

  float4 acc = make_float4(0.f, 0.f, 0.f, 0.f);
  bool any = false;
#pragma unroll 4
  for (int i = p0; i < p1; ++i) {
    while (i >= offs[k + 1]) {
      if (any) {
        float* dst = sums + (size_t)k * DIM + lane * 4;
        atomicAdd(dst + 0, acc.x); atomicAdd(dst + 1, acc.y);
        atomicAdd(dst + 2, acc.z); atomicAdd(dst + 3, acc.w);
        acc = make_float4(0.f, 0.f, 0.f, 0.f);
        any = false;
      }
      ++k;
    }
    int pid = plist[i];
    float4 v = ((const float4*)x)[(size_t)pid * 64 + lane];
    acc.x += v.x; acc.y += v.y; acc.z += v.z; acc.w += v.w;
    any = true;
  }
  if (any) {
    float* dst = sums + (size_t)k * DIM + lane * 4;
    atomicAdd(dst + 0, acc.x); atomicAdd(dst + 1, acc.y);
    atomicAdd(dst + 2, acc.z); atomicAdd(dst + 3, acc.w);
  }
}

__global__ __launch_bounds__(256)
void ema_kernel(const float* __restrict__ c, const float* __restrict__ sums,
                const int* __restrict__ counts, float* __restrict__ outc) {
  int k = blockIdx.x;
  int d = threadIdx.x;
  float cnt = (float)counts[k];
  size_t o = (size_t)k * DIM + d;
  float nc = sums[o] / cnt;
  outc[o] = 0.9f * c[o] + 0.1f * nc;
}

// ---------- round-1 ballot sums (fallback path only) ----------
#define GB 4
#define SLICES 8
__global__ __launch_bounds__(256)
void sums_kernel(const float* __restrict__ x, const int* __restrict__ idx,
                 float* __restrict__ sums, int* __restrict__ counts) {
  const int groups = KTOT / GB;
  const int group = blockIdx.x % groups;
  const int slice = blockIdx.x / groups;
  const int kg0 = group * GB;
  const int tid = threadIdx.x;
  const int lane = tid & 63;
  const int w = tid >> 6;
  const int per_slice = NPTS / SLICES;
  const int nbeg = slice * per_slice;

  float4 acc[GB];
  int cnt[GB];
#pragma unroll
  for (int j = 0; j < GB; ++j) { acc[j] = make_float4(0.f, 0.f, 0.f, 0.f); cnt[j] = 0; }

  for (int it = 0; it < per_slice; it += 256) {
    int n = nbeg + it + tid;
    int k = idx[n];
#pragma unroll
    for (int j = 0; j < GB; ++j) {
      unsigned long long m = __ballot(k == kg0 + j);
      while (m) {
        int src = __ffsll((unsigned long long)m) - 1;
        int nn = __shfl(n, src);
        float4 v = ((const float4*)(x + (size_t)nn * DIM))[lane];
        acc[j].x += v.x; acc[j].y += v.y; acc[j].z += v.z; acc[j].w += v.w;
        cnt[j]++;
        m &= (m - 1);
      }
    }
  }

  __shared__ __align__(16) float lacc[4][GB][DIM];
  __shared__ int lcnt[4][GB];
#pragma unroll
  for (int j = 0; j < GB; ++j) ((float4*)&lacc[w][j][0])[lane] = acc[j];
  if (lane == 0) {
#pragma unroll
    for (int j = 0; j < GB; ++j) lcnt[w][j] = cnt[j];
  }
  __syncthreads();
#pragma unroll
  for (int j = 0; j < GB; ++j) {
    float s = lacc[0][j][tid] + lacc[1][j][tid] + lacc[2][j][tid] + lacc[3][j][tid];
    atomicAdd(&sums[(size_t)(kg0 + j) * DIM + tid], s);
  }
  if (tid < GB) {
    int ct = lcnt[0][tid] + lcnt[1][tid] + lcnt[2][tid] + lcnt[3][tid];
    atomicAdd(&counts[kg0 + tid], ct);
  }
}

// ================= round-1 fallback assign (if ws too small) =================
__global__ __launch_bounds__(256, 2)
void assign_kernel_r1(const float* __restrict__ x, const float* __restrict__ c,
                      const double* __restrict__ c2, float* __restrict__ out,
                      int* __restrict__ idx_out) {
  __shared__ __align__(16) float xs[DIM * MP];
  __shared__ __align__(16) float cs[DT * KT];
  const int tid = threadIdx.x;
  const int p0 = blockIdx.x * MP;
  const int tp = tid & 15;
  const int tk = tid >> 4;
  {
    const int p = tid >> 2;
    const int dg = tid & 3;
    const float4* x4 = (const float4*)(x + (size_t)(p0 + p) * DIM);
#pragma unroll
    for (int r = 0; r < 16; ++r) {
      int d4 = r * 4 + dg;
      float4 v = x4[d4];
      int dbase = d4 * 4;
      xs[(dbase + 0) * MP + p] = v.x;
      xs[(dbase + 1) * MP + p] = v.y;
      xs[(dbase + 2) * MP + p] = v.z;
      xs[(dbase + 3) * MP + p] = v.w;
    }
  }
  double best[4]; int bestk[4];
#pragma unroll
  for (int i = 0; i < 4; ++i) { best[i] = 1e300; bestk[i] = 0; }
  for (int kc = 0; kc < KTOT / KT; ++kc) {
    const int k0 = kc * KT;
    double dacc[4][4];
#pragma unroll
    for (int i = 0; i < 4; ++i)
#pragma unroll
      for (int j = 0; j < 4; ++j) dacc[i][j] = 0.0;
    for (int dc = 0; dc < DIM / DT; ++dc) {
      __syncthreads();
      {
        const int kl = tid >> 2;
        const int dg = tid & 3;
        const float4* c4 = (const float4*)(c + (size_t)(k0 + kl) * DIM + dc * DT);
#pragma unroll
        for (int h = 0; h < 2; ++h) {
          int dq = h * 4 + dg;
          float4 v = c4[dq];
          int dbase = dq * 4;
          cs[(dbase + 0) * KT + kl] = v.x;
          cs[(dbase + 1) * KT + kl] = v.y;
          cs[(dbase + 2) * KT + kl] = v.z;
          cs[(dbase + 3) * KT + kl] = v.w;
        }
      }
      __syncthreads();
      float acc[4][4];
#pragma unroll
      for (int i = 0; i < 4; ++i)
#pragma unroll
        for (int j = 0; j < 4; ++j) acc[i][j] = 0.0f;
#pragma unroll
      for (int d = 0; d < DT; ++d) {
        float4 xv = ((const float4*)(xs + (size_t)(dc * DT + d) * MP))[tp];
        float4 cv = ((const float4*)(cs + (size_t)d * KT))[tk];
        float xa[4] = {xv.x, xv.y, xv.z, xv.w};
        float ca[4] = {cv.x, cv.y, cv.z, cv.w};
#pragma unroll
        for (int i = 0; i < 4; ++i)
#pragma unroll
          for (int j = 0; j < 4; ++j) acc[i][j] = fmaf(xa[i], ca[j], acc[i][j]);
      }
#pragma unroll
      for (int i = 0; i < 4; ++i)
#pragma unroll
        for (int j = 0; j < 4; ++j) dacc[i][j] += (double)acc[i][j];
    }
#pragma unroll
    for (int j = 0; j < 4; ++j) {
      int k = k0 + tk * 4 + j;
      double c2v = c2[k];
#pragma unroll
      for (int i = 0; i < 4; ++i) {
        double s = c2v - 2.0 * dacc[i][j];
        if (s < best[i]) { best[i] = s; bestk[i] = k; }
      }
    }
  }
  __syncthreads();
  double* redv = (double*)cs;
  int* redk = (int*)xs;
  int* bk = (int*)xs + 1024;
#pragma unroll
  for (int i = 0; i < 4; ++i) {
    int p = tp * 4 + i;
    redv[tk * MP + p] = best[i];
    redk[tk * MP + p] = bestk[i];
  }
  __syncthreads();
  if (tid < MP) {
    int p = tid;
    double bv = redv[p]; int bkk = redk[p];
#pragma unroll
    for (int t = 1; t < 16; ++t) {
      double v = redv[t * MP + p]; int kk = redk[t * MP + p];
      if (v < bv || (v == bv && kk < bkk)) { bv = v; bkk = kk; }
    }
    bk[p] = bkk;
    idx_out[p0 + p] = bkk;
  }
  __syncthreads();
  float* orow = out + (size_t)p0 * KTOT;
  for (int l = tid; l < MP * KTOT; l += 256) {
    int p = l >> 9;
    int k = l & (KTOT - 1);
    orow[l] = (k == bk[p]) ? 1.0f : 0.0f;
  }
}

extern "C" void kernel_launch(void* const* d_in, const int* in_sizes, int n_in,
                              void* d_out, int out_size, void* d_ws, size_t ws_size,
                              hipStream_t stream) {
  const float* x = (const float*)d_in[0];
  const float* c = (const float*)d_in[1];
  float* out = (float*)d_out;
  float* outc = out + (size_t)NPTS * KTOT;

  char* ws = (char*)d_ws;

  if (ws_size >= WS_MAIN_NEED) {
    double* c2   = (double*)(ws + 0);
    u16* Ch      = (u16*)(ws + 4096);
    u16* Cl      = (u16*)(ws + 266240);
    int* idx     = (int*)(ws + 528384);
    float* pv1   = (float*)(ws + 1052672);
    int* pk1     = (int*)(ws + 3149824);
    float* pv2   = (float*)(ws + 5246976);
    float* sums  = (float*)(ws + 7344128);
    int* counts  = (int*)(ws + 7868416);
    int* flagcnt = (int*)(ws + 7870464);
    int* flaglist= (int*)(ws + 7870528);
    // overlays (dead after combine):
    int* offsets = (int*)(ws + 1052672);            // 513 ints, over pv1
    int* cursors = (int*)(ws + 1052672 + 4096);     // 512 ints, over pv1
    int* plist   = (int*)(ws + 5246976);            // 131072 ints, over pv2

    hipMemsetAsync(sums, 0, (size_t)(KTOT * DIM + KTOT) * 4, stream);  // sums + counts
    hipMemsetAsync(flagcnt, 0, 64, stream);
    c2_kernel<<<KTOT, 64, 0, stream>>>(c, c2);
    csplit_kernel<<<64, 256, 0, stream>>>(c, Ch, Cl);
    gemm_topk_kernel<<<4096, 256, 0, stream>>>(x, Ch, Cl, c2, pv1, pk1, pv2);
    combine_kernel<<<NPTS / 256, 256, 0, stream>>>(pv1, pk1, pv2, idx, flagcnt, flaglist);
    refine_batch_kernel<<<256, 256, 0, stream>>>(x, c, c2, flagcnt, flaglist, idx);
    onehot_kernel<<<NPTS / 32, 256, 0, stream>>>(idx, out);
    hist_kernel<<<NPTS / 1024, 256, 0, stream>>>(idx, counts);
    scan_kernel<<<1, 512, 0, stream>>>(counts, offsets, cursors);
    scatter_kernel<<<NPTS / 1024, 256, 0, stream>>>(idx, cursors, plist);
    gathersum_flat_kernel<<<NPTS / 32 / 4, 256, 0, stream>>>(x, plist, offsets, sums);
    ema_kernel<<<KTOT, DIM, 0, stream>>>(c, sums, counts, outc);
  } else {
    // round-1 fallback (ws >= 1.05 MB proven)
    double* c2  = (double*)ws;
    int* idx    = (int*)(ws + 4096);
    float* sums = (float*)(ws + 4096 + 524288);
    int* counts = (int*)(ws + 4096 + 524288 + 524288);
    hipMemsetAsync(sums, 0, (size_t)(KTOT * DIM + KTOT) * 4, stream);
    c2_kernel<<<KTOT, 64, 0, stream>>>(c, c2);
    assign_kernel_r1<<<NPTS / MP, 256, 0, stream>>>(x, c, c2, out, idx);
    sums_kernel<<<(KTOT / GB) * SLICES, 256, 0, stream>>>(x, idx, sums, counts);
    ema_kernel<<<KTOT, DIM, 0, stream>>>(c, sums, counts, outc);
  }
}

// Round 6
// 696.612 us; speedup vs baseline: 1.2718x; 1.2718x over previous
//
#include <hip/hip_runtime.h>
#include <hip/hip_fp16.h>

#define NPTS 131072   // B*S = 128*1024
#define DIM  256
#define KTOT 512
#define GAP_T 0.012f

typedef unsigned short u16;
typedef _Float16 half8 __attribute__((ext_vector_type(8)));
typedef float floatx4 __attribute__((ext_vector_type(4)));

// ---------------- ws layout (main path) ----------------
// 0        : c2 double[512]                    (4096)
// 4096     : Ch u16[512*256]                   (262144)
// 266240   : Cl u16[512*256]                   (262144)
// 528384   : idx int[131072]                   (524288)
// 1052672  : pv1 float[4][131072]              (2097152)   | after combine: offsets int[513], cursors int[512]
// 3149824  : pk1 int[4][131072]                (2097152)
// 5246976  : pv2 float[4][131072]              (2097152)   | after combine: plist int[131072]
// 7344128  : sums float[512*256]               (524288)
// 7868416  : counts int[512]                   (2048)
// 7870464  : flagcnt int[16]                   (64)
// 7870528  : flaglist int[131072]              (524288)
#define WS_MAIN_NEED 8394816u

// ---------- c2 in fp64 (shared by both paths) ----------
__global__ __launch_bounds__(64)
void c2_kernel(const float* __restrict__ c, double* __restrict__ c2) {
  int k = blockIdx.x;
  int lane = threadIdx.x;
  const float* row = c + (size_t)k * DIM;
  double s = 0.0;
#pragma unroll
  for (int r = 0; r < DIM / 64; ++r) {
    float v = row[r * 64 + lane];
    s += (double)v * (double)v;
  }
#pragma unroll
  for (int off = 32; off > 0; off >>= 1) s += __shfl_down(s, off);
  if (lane == 0) c2[k] = s;
}

// ---------- pre-split centroids into hi/lo fp16, swizzled chunk layout ----------
__global__ __launch_bounds__(256)
void csplit_kernel(const float* __restrict__ c, u16* __restrict__ Ch, u16* __restrict__ Cl) {
  int id = blockIdx.x * 256 + threadIdx.x;   // 16384 units
  int n = id >> 5;          // 0..511
  int cg = id & 31;         // global 8-chunk 0..31
  int kc = cg >> 3, cc = cg & 7;
  const float* src = c + (size_t)n * DIM + cg * 8;
  half8 hv, lv;
#pragma unroll
  for (int e = 0; e < 8; ++e) {
    float f = src[e];
    _Float16 h = (_Float16)f;
    hv[e] = h;
    lv[e] = (_Float16)(f - (float)h);
  }
  size_t dst = (size_t)n * DIM + kc * 64 + (size_t)(cc ^ (n & 7)) * 8;
  *(half8*)(Ch + dst) = hv;
  *(half8*)(Cl + dst) = lv;
}

// ---------- MFMA split-fp16 GEMM + per-(block,n-tile) top-2 ----------
__device__ __forceinline__ void load_lds16(const void* g, void* l) {
  __builtin_amdgcn_global_load_lds((const __attribute__((address_space(1))) void*)g,
                                   (__attribute__((address_space(3))) void*)l, 16, 0, 0);
}

__global__ __launch_bounds__(256)
void gemm_topk_kernel(const float* __restrict__ x, const u16* __restrict__ Ch,
                      const u16* __restrict__ Cl, const double* __restrict__ c2,
                      float* __restrict__ pv1, int* __restrict__ pk1, float* __restrict__ pv2) {
  __shared__ __align__(16) unsigned char smem[128 * 132 * 4];  // 67.6 KB, reused
  __shared__ float rb_v[128], rb_v2[128];
  __shared__ int rb_k[128];
  u16* Ah = (u16*)smem;            // [128][64]
  u16* Al = Ah + 8192;
  u16* Bh = Al + 8192;
  u16* Bl = Bh + 8192;

  const int tid = threadIdx.x;
  const int bx = blockIdx.x;
  // XCD-aware swizzle: the 4 n-blocks sharing an A-tile get equal bx%8 (same XCD
  // under round-robin dispatch) so the A-tile stays in that XCD's L2.
  const int nblk = (bx >> 3) & 3;
  const int mblk = (bx & 7) + ((bx >> 5) << 3);
  const int m0 = mblk * 128, n0 = nblk * 128;
  const int w = tid >> 6, lane = tid & 63;
  const int wm = (w & 1) * 64, wn = (w >> 1) * 64;
  const int lm = lane & 15, quad = lane >> 4;

  floatx4 acc[4][4] = {};

  for (int kc = 0; kc < 4; ++kc) {
    const int k0 = kc * 64;
    __syncthreads();
#pragma unroll
    for (int i = 0; i < 4; ++i) {
      int s = i * 256 + tid;
      int row = s >> 3, pos = s & 7;
      size_t go = (size_t)(n0 + row) * DIM + k0 + pos * 8;
      load_lds16(Ch + go, Bh + (size_t)s * 8);
      load_lds16(Cl + go, Bl + (size_t)s * 8);
    }
#pragma unroll
    for (int i = 0; i < 4; ++i) {
      int s = i * 256 + tid;
      int row = s >> 3, kg = s & 7;
      const float4* gx = (const float4*)(x + (size_t)(m0 + row) * DIM + k0 + kg * 8);
      float4 f0 = gx[0], f1 = gx[1];
      float fv[8] = {f0.x, f0.y, f0.z, f0.w, f1.x, f1.y, f1.z, f1.w};
      half8 hv, lv;
#pragma unroll
      for (int e = 0; e < 8; ++e) {
        _Float16 h = (_Float16)fv[e];
        hv[e] = h;
        lv[e] = (_Float16)(fv[e] - (float)h);
      }
      int pos = kg ^ (row & 7);
      *(half8*)(Ah + (size_t)row * 64 + pos * 8) = hv;
      *(half8*)(Al + (size_t)row * 64 + pos * 8) = lv;
    }
    __syncthreads();

#pragma unroll
    for (int s = 0; s < 2; ++s) {
      half8 ah[4], al[4], bh[4], bl[4];
#pragma unroll
      for (int t = 0; t < 4; ++t) {
        int m = wm + t * 16 + lm;
        int pa = ((s * 4 + quad) ^ (m & 7)) * 8;
        ah[t] = *(const half8*)(Ah + (size_t)m * 64 + pa);
        al[t] = *(const half8*)(Al + (size_t)m * 64 + pa);
        int n = wn + t * 16 + lm;
        int pb = ((s * 4 + quad) ^ (n & 7)) * 8;
        bh[t] = *(const half8*)(Bh + (size_t)n * 64 + pb);
        bl[t] = *(const half8*)(Bl + (size_t)n * 64 + pb);
      }
#pragma unroll
      for (int mt = 0; mt < 4; ++mt)
#pragma unroll
        for (int nt = 0; nt < 4; ++nt) {
          acc[mt][nt] = __builtin_amdgcn_mfma_f32_16x16x32_f16(ah[mt], bh[nt], acc[mt][nt], 0, 0, 0);
          acc[mt][nt] = __builtin_amdgcn_mfma_f32_16x16x32_f16(ah[mt], bl[nt], acc[mt][nt], 0, 0, 0);
          acc[mt][nt] = __builtin_amdgcn_mfma_f32_16x16x32_f16(al[mt], bh[nt], acc[mt][nt], 0, 0, 0);
        }
    }
  }

  // ---- epilogue: scores to LDS (stride 132), per-row top-2
  __syncthreads();
  float* sc = (float*)smem;
  float c2f[4];
#pragma unroll
  for (int nt = 0; nt < 4; ++nt) c2f[nt] = (float)c2[n0 + wn + nt * 16 + lm];
#pragma unroll
  for (int mt = 0; mt < 4; ++mt)
#pragma unroll
    for (int nt = 0; nt < 4; ++nt)
#pragma unroll
      for (int r = 0; r < 4; ++r) {
        int m = wm + mt * 16 + quad * 4 + r;
        int n = wn + nt * 16 + lm;
        sc[m * 132 + n] = c2f[nt] - 2.0f * acc[mt][nt][r];
      }
  __syncthreads();

  {
    int r = tid >> 1, h = tid & 1;
    const float4* rowp4 = (const float4*)(sc + r * 132 + h * 64);
    float bv = 1e30f, sv = 1e30f;
    int bk = 0;
#pragma unroll
    for (int j4 = 0; j4 < 16; ++j4) {
      float4 v4 = rowp4[j4];
      float va[4] = {v4.x, v4.y, v4.z, v4.w};
#pragma unroll
      for (int e = 0; e < 4; ++e) {
        float v = va[e];
        if (v < bv) { sv = bv; bv = v; bk = n0 + h * 64 + j4 * 4 + e; }
        else if (v < sv) sv = v;
      }
    }
    if (h == 1) { rb_v[r] = bv; rb_k[r] = bk; rb_v2[r] = sv; }
    __syncthreads();
    if (h == 0) {
      float ov = rb_v[r], ov2 = rb_v2[r];
      int ok = rb_k[r];
      float fbv, fsv; int fbk;
      if (ov < bv) { fbv = ov; fbk = ok; fsv = fminf(bv, ov2); }
      else         { fbv = bv; fbk = bk; fsv = fminf(sv, ov); }  // tie keeps lower k (h=0)
      int m = m0 + r;
      pv1[(size_t)nblk * NPTS + m] = fbv;
      pk1[(size_t)nblk * NPTS + m] = fbk;
      pv2[(size_t)nblk * NPTS + m] = fsv;
    }
  }
}

// ---------- merge 4 n-block partials -> idx + flag near-ties ----------
__global__ __launch_bounds__(256)
void combine_kernel(const float* __restrict__ pv1, const int* __restrict__ pk1,
                    const float* __restrict__ pv2, int* __restrict__ idx,
                    int* __restrict__ flagcnt, int* __restrict__ flaglist) {
  int m = blockIdx.x * 256 + threadIdx.x;
  float bv = 1e30f, sv = 1e30f;
  int bk = 0;
#pragma unroll
  for (int b = 0; b < 4; ++b) {     // ascending b = ascending k: tie keeps lower k
    float v1 = pv1[(size_t)b * NPTS + m];
    int k1 = pk1[(size_t)b * NPTS + m];
    float v2 = pv2[(size_t)b * NPTS + m];
    if (v1 < bv) { sv = fminf(bv, v2); bv = v1; bk = k1; }
    else { sv = fminf(sv, v1); }
  }
  idx[m] = bk;
  if (sv - bv < GAP_T) {
    int p = atomicAdd(flagcnt, 1);
    flaglist[p] = m;
  }
}

// ---------- exact re-check of flagged points: one point per block (max TLP) ----------
__global__ __launch_bounds__(256)
void refine_kernel(const float* __restrict__ x, const float* __restrict__ c,
                   const double* __restrict__ c2, const int* __restrict__ flagcnt,
                   const int* __restrict__ flaglist, int* __restrict__ idx) {
  __shared__ __align__(16) float xs[DIM];
  __shared__ double rv[256];
  __shared__ int rk[256];
  int cnt = *(volatile const int*)flagcnt;
  for (int i = blockIdx.x; i < cnt; i += gridDim.x) {
    __syncthreads();
    int m = flaglist[i];
    if (threadIdx.x < 64)
      ((float4*)xs)[threadIdx.x] = ((const float4*)(x + (size_t)m * DIM))[threadIdx.x];
    __syncthreads();
    double bestv = 1e300; int bestk = 0;
#pragma unroll
    for (int half = 0; half < 2; ++half) {
      int k = half * 256 + threadIdx.x;
      const float* crow = c + (size_t)k * DIM;
      double dacc = 0.0;
#pragma unroll
      for (int dc = 0; dc < 8; ++dc) {
        float f = 0.0f;
#pragma unroll
        for (int d = 0; d < 32; ++d) f = fmaf(xs[dc * 32 + d], crow[dc * 32 + d], f);
        dacc += (double)f;
      }
      double s = c2[k] - 2.0 * dacc;
      if (s < bestv || (s == bestv && k < bestk)) { bestv = s; bestk = k; }
    }
    rv[threadIdx.x] = bestv; rk[threadIdx.x] = bestk;
    __syncthreads();
    for (int off = 128; off > 0; off >>= 1) {
      if (threadIdx.x < off) {
        double v = rv[threadIdx.x + off]; int kk = rk[threadIdx.x + off];
        if (v < rv[threadIdx.x] || (v == rv[threadIdx.x] && kk < rk[threadIdx.x])) {
          rv[threadIdx.x] = v; rk[threadIdx.x] = kk;
        }
      }
      __syncthreads();
    }
    if (threadIdx.x == 0) idx[m] = rk[0];
  }
}

// ---------- one-hot write ----------
__global__ __launch_bounds__(256)
void onehot_kernel(const int* __restrict__ idx, float* __restrict__ out) {
  __shared__ int bk[32];
  int b = blockIdx.x;  // 32 points per block
  if (threadIdx.x < 32) bk[threadIdx.x] = idx[b * 32 + threadIdx.x];
  __syncthreads();
  float4* o = (float4*)(out + (size_t)b * 32 * KTOT);
#pragma unroll
  for (int j = 0; j < 16; ++j) {
    int f4 = j * 256 + threadIdx.x;   // 0..4095
    int p = f4 >> 7;                  // 128 float4 per row
    int n4 = (f4 & 127) * 4;
    int k = bk[p];
    float4 v;
    v.x = (k == n4 + 0) ? 1.0f : 0.0f;
    v.y = (k == n4 + 1) ? 1.0f : 0.0f;
    v.z = (k == n4 + 2) ? 1.0f : 0.0f;
    v.w = (k == n4 + 3) ? 1.0f : 0.0f;
    o[f4] = v;
  }
}

// ================= counting-sort sums pipeline =================
__global__ __launch_bounds__(256)
void hist_kernel(const int* __restrict__ idx, int* __restrict__ counts) {
  __shared__ int h[KTOT];
  int t = threadIdx.x;
#pragma unroll
  for (int i = 0; i < KTOT / 256; ++i) h[i * 256 + t] = 0;
  __syncthreads();
  int base = blockIdx.x * 1024 + t;
#pragma unroll
  for (int j = 0; j < 4; ++j) atomicAdd(&h[idx[base + j * 256]], 1);
  __syncthreads();
#pragma unroll
  for (int i = 0; i < KTOT / 256; ++i) {
    int v = h[i * 256 + t];
    if (v) atomicAdd(&counts[i * 256 + t], v);
  }
}

__global__ __launch_bounds__(512)
void scan_kernel(const int* __restrict__ counts, int* __restrict__ offsets,
                 int* __restrict__ cursors) {
  __shared__ int s[KTOT];
  int t = threadIdx.x;
  int mine = counts[t];
  s[t] = mine;
  __syncthreads();
  for (int off = 1; off < KTOT; off <<= 1) {
    int v = (t >= off) ? s[t - off] : 0;
    __syncthreads();
    s[t] += v;
    __syncthreads();
  }
  int excl = s[t] - mine;
  offsets[t] = excl;
  cursors[t] = excl;
  if (t == KTOT - 1) offsets[KTOT] = s[t];
}

__global__ __launch_bounds__(256)
void scatter_kernel(const int* __restrict__ idx, int* __restrict__ cursors,
                    int* __restrict__ plist) {
  int base = blockIdx.x * 1024 + threadIdx.x;
#pragma unroll
  for (int j = 0; j < 4; ++j) {
    int n = base + j * 256;
    int k = idx[n];
    int pos = atomicAdd(&cursors[k], 1);
    plist[pos] = n;
  }
}

// gathersum_flat: skew-proof — every wave owns 32 consecutive sorted positions.
__global__ __launch_bounds__(256)
void gathersum_flat_kernel(const float* __restrict__ x, const int* __restrict__ plist,
                           const int* __restrict__ offsets, float* __restrict__ sums) {
  __shared__ int offs[KTOT + 1];
  for (int t = threadIdx.x; t < KTOT + 1; t += 256) offs[t] = offsets[t];
  __syncthreads();
  const int w = threadIdx.x >> 6, lane = threadIdx.x & 63;
  const int wid = blockIdx.x * 4 + w;   // 4096 waves total
  const int p0 = wid * 32, p1 = p0 + 32;

  int lo = 0, hi = KTOT;
  while (hi - lo > 1) { int mid = (lo + hi) >> 1; if (offs[mid] <= p0) lo = mid; else hi = mid; }
  int k = lo;

  float4 acc = make_float4(0.f, 0.f, 0.f, 0.f);
  bool any = false;
#pragma unroll 4
  for (int i = p0; i < p1; ++i) {
    while (i >= offs[k + 1]) {
      if (any) {
        float* dst = sums + (size_t)k * DIM + lane * 4;
        atomicAdd(dst + 0, acc.x); atomicAdd(dst + 1, acc.y);
        atomicAdd(dst + 2, acc.z); atomicAdd(dst + 3, acc.w);
        acc = make_float4(0.f, 0.f, 0.f, 0.f);
        any = false;
      }
      ++k;
    }
    int pid = plist[i];
    float4 v = ((const float4*)x)[(size_t)pid * 64 + lane];
    acc.x += v.x; acc.y += v.y; acc.z += v.z; acc.w += v.w;
    any = true;
  }
  if (any) {
    float* dst = sums + (size_t)k * DIM + lane * 4;
    atomicAdd(dst + 0, acc.x); atomicAdd(dst + 1, acc.y);
    atomicAdd(dst + 2, acc.z); atomicAdd(dst + 3, acc.w);
  }
}

__global__ __launch_bounds__(256)
void ema_kernel(const float* __restrict__ c, const float* __restrict__ sums,
                const int* __restrict__ counts, float* __restrict__ outc) {
  int k = blockIdx.x;
  int d = threadIdx.x;
  float cnt = (float)counts[k];
  size_t o = (size_t)k * DIM + d;
  float nc = sums[o] / cnt;
  outc[o] = 0.9f * c[o] + 0.1f * nc;
}

// ---------- round-1 ballot sums (fallback path only) ----------
#define GB 4
#define SLICES 8
__global__ __launch_bounds__(256)
void sums_kernel(const float* __restrict__ x, const int* __restrict__ idx,
                 float* __restrict__ sums, int* __restrict__ counts) {
  const int groups = KTOT / GB;
  const int group = blockIdx.x % groups;
  const int slice = blockIdx.x / groups;
  const int kg0 = group * GB;
  const int tid = threadIdx.x;
  const int lane = tid & 63;
  const int w = tid >> 6;
  const int per_slice = NPTS / SLICES;
  const int nbeg = slice * per_slice;

  float4 acc[GB];
  int cnt[GB];
#pragma unroll
  for (int j = 0; j < GB; ++j) { acc[j] = make_float4(0.f, 0.f, 0.f, 0.f); cnt[j] = 0; }

  for (int it = 0; it < per_slice; it += 256) {
    int n = nbeg + it + tid;
    int k = idx[n];
#pragma unroll
    for (int j = 0; j < GB; ++j) {
      unsigned long long m = __ballot(k == kg0 + j);
      while (m) {
        int src = __ffsll((unsigned long long)m) - 1;
        int nn = __shfl(n, src);
        float4 v = ((const float4*)(x + (size_t)nn * DIM))[lane];
        acc[j].x += v.x; acc[j].y += v.y; acc[j].z += v.z; acc[j].w += v.w;
        cnt[j]++;
        m &= (m - 1);
      }
    }
  }

  __shared__ __align__(16) float lacc[4][GB][DIM];
  __shared__ int lcnt[4][GB];
#pragma unroll
  for (int j = 0; j < GB; ++j) ((float4*)&lacc[w][j][0])[lane] = acc[j];
  if (lane == 0) {
#pragma unroll
    for (int j = 0; j < GB; ++j) lcnt[w][j] = cnt[j];
  }
  __syncthreads();
#pragma unroll
  for (int j = 0; j < GB; ++j) {
    float s = lacc[0][j][tid] + lacc[1][j][tid] + lacc[2][j][tid] + lacc[3][j][tid];
    atomicAdd(&sums[(size_t)(kg0 + j) * DIM + tid], s);
  }
  if (tid < GB) {
    int ct = lcnt[0][tid] + lcnt[1][tid] + lcnt[2][tid] + lcnt[3][tid];
    atomicAdd(&counts[kg0 + tid], ct);
  }
}

// ================= round-1 fallback assign (if ws too small) =================
#define MP 64
#define KT 64
#define DT 32
__global__ __launch_bounds__(256, 2)
void assign_kernel_r1(const float* __restrict__ x, const float* __restrict__ c,
                      const double* __restrict__ c2, float* __restrict__ out,
                      int* __restrict__ idx_out) {
  __shared__ __align__(16) float xs[DIM * MP];
  __shared__ __align__(16) float cs[DT * KT];
  const int tid = threadIdx.x;
  const int p0 = blockIdx.x * MP;
  const int tp = tid & 15;
  const int tk = tid >> 4;
  {
    const int p = tid >> 2;
    const int dg = tid & 3;
    const float4* x4 = (const float4*)(x + (size_t)(p0 + p) * DIM);
#pragma unroll
    for (int r = 0; r < 16; ++r) {
      int d4 = r * 4 + dg;
      float4 v = x4[d4];
      int dbase = d4 * 4;
      xs[(dbase + 0) * MP + p] = v.x;
      xs[(dbase + 1) * MP + p] = v.y;
      xs[(dbase + 2) * MP + p] = v.z;
      xs[(dbase + 3) * MP + p] = v.w;
    }
  }
  double best[4]; int bestk[4];
#pragma unroll
  for (int i = 0; i < 4; ++i) { best[i] = 1e300; bestk[i] = 0; }
  for (int kc = 0; kc < KTOT / KT; ++kc) {
    const int k0 = kc * KT;
    double dacc[4][4];
#pragma unroll
    for (int i = 0; i < 4; ++i)
#pragma unroll
      for (int j = 0; j < 4; ++j) dacc[i][j] = 0.0;
    for (int dc = 0; dc < DIM / DT; ++dc) {
      __syncthreads();
      {
        const int kl = tid >> 2;
        const int dg = tid & 3;
        const float4* c4 = (const float4*)(c + (size_t)(k0 + kl) * DIM + dc * DT);
#pragma unroll
        for (int h = 0; h < 2; ++h) {
          int dq = h * 4 + dg;
          float4 v = c4[dq];
          int dbase = dq * 4;
          cs[(dbase + 0) * KT + kl] = v.x;
          cs[(dbase + 1) * KT + kl] = v.y;
          cs[(dbase + 2) * KT + kl] = v.z;
          cs[(dbase + 3) * KT + kl] = v.w;
        }
      }
      __syncthreads();
      float acc[4][4];
#pragma unroll
      for (int i = 0; i < 4; ++i)
#pragma unroll
        for (int j = 0; j < 4; ++j) acc[i][j] = 0.0f;
#pragma unroll
      for (int d = 0; d < DT; ++d) {
        float4 xv = ((const float4*)(xs + (size_t)(dc * DT + d) * MP))[tp];
        float4 cv = ((const float4*)(cs + (size_t)d * KT))[tk];
        float xa[4] = {xv.x, xv.y, xv.z, xv.w};
        float ca[4] = {cv.x, cv.y, cv.z, cv.w};
#pragma unroll
        for (int i = 0; i < 4; ++i)
#pragma unroll
          for (int j = 0; j < 4; ++j) acc[i][j] = fmaf(xa[i], ca[j], acc[i][j]);
      }
#pragma unroll
      for (int i = 0; i < 4; ++i)
#pragma unroll
        for (int j = 0; j < 4; ++j) dacc[i][j] += (double)acc[i][j];
    }
#pragma unroll
    for (int j = 0; j < 4; ++j) {
      int k = k0 + tk * 4 + j;
      double c2v = c2[k];
#pragma unroll
      for (int i = 0; i < 4; ++i) {
        double s = c2v - 2.0 * dacc[i][j];
        if (s < best[i]) { best[i] = s; bestk[i] = k; }
      }
    }
  }
  __syncthreads();
  double* redv = (double*)cs;
  int* redk = (int*)xs;
  int* bk = (int*)xs + 1024;
#pragma unroll
  for (int i = 0; i < 4; ++i) {
    int p = tp * 4 + i;
    redv[tk * MP + p] = best[i];
    redk[tk * MP + p] = bestk[i];
  }
  __syncthreads();
  if (tid < MP) {
    int p = tid;
    double bv = redv[p]; int bkk = redk[p];
#pragma unroll
    for (int t = 1; t < 16; ++t) {
      double v = redv[t * MP + p]; int kk = redk[t * MP + p];
      if (v < bv || (v == bv && kk < bkk)) { bv = v; bkk = kk; }
    }
    bk[p] = bkk;
    idx_out[p0 + p] = bkk;
  }
  __syncthreads();
  float* orow = out + (size_t)p0 * KTOT;
  for (int l = tid; l < MP * KTOT; l += 256) {
    int p = l >> 9;
    int k = l & (KTOT - 1);
    orow[l] = (k == bk[p]) ? 1.0f : 0.0f;
  }
}

extern "C" void kernel_launch(void* const* d_in, const int* in_sizes, int n_in,
                              void* d_out, int out_size, void* d_ws, size_t ws_size,
                              hipStream_t stream) {
  const float* x = (const float*)d_in[0];
  const float* c = (const float*)d_in[1];
  float* out = (float*)d_out;
  float* outc = out + (size_t)NPTS * KTOT;

  char* ws = (char*)d_ws;

  if (ws_size >= WS_MAIN_NEED) {
    double* c2   = (double*)(ws + 0);
    u16* Ch      = (u16*)(ws + 4096);
    u16* Cl      = (u16*)(ws + 266240);
    int* idx     = (int*)(ws + 528384);
    float* pv1   = (float*)(ws + 1052672);
    int* pk1     = (int*)(ws + 3149824);
    float* pv2   = (float*)(ws + 5246976);
    float* sums  = (float*)(ws + 7344128);
    int* counts  = (int*)(ws + 7868416);
    int* flagcnt = (int*)(ws + 7870464);
    int* flaglist= (int*)(ws + 7870528);
    // overlays (dead after combine):
    int* offsets = (int*)(ws + 1052672);            // 513 ints, over pv1
    int* cursors = (int*)(ws + 1052672 + 4096);     // 512 ints, over pv1
    int* plist   = (int*)(ws + 5246976);            // 131072 ints, over pv2

    hipMemsetAsync(sums, 0, (size_t)(KTOT * DIM + KTOT) * 4, stream);  // sums + counts
    hipMemsetAsync(flagcnt, 0, 64, stream);
    c2_kernel<<<KTOT, 64, 0, stream>>>(c, c2);
    csplit_kernel<<<64, 256, 0, stream>>>(c, Ch, Cl);
    gemm_topk_kernel<<<4096, 256, 0, stream>>>(x, Ch, Cl, c2, pv1, pk1, pv2);
    combine_kernel<<<NPTS / 256, 256, 0, stream>>>(pv1, pk1, pv2, idx, flagcnt, flaglist);
    refine_kernel<<<1024, 256, 0, stream>>>(x, c, c2, flagcnt, flaglist, idx);
    onehot_kernel<<<NPTS / 32, 256, 0, stream>>>(idx, out);
    hist_kernel<<<NPTS / 1024, 256, 0, stream>>>(idx, counts);
    scan_kernel<<<1, 512, 0, stream>>>(counts, offsets, cursors);
    scatter_kernel<<<NPTS / 1024, 256, 0, stream>>>(idx, cursors, plist);
    gathersum_flat_kernel<<<NPTS / 32 / 4, 256, 0, stream>>>(x, plist, offsets, sums);
    ema_kernel<<<KTOT, DIM, 0, stream>>>(c, sums, counts, outc);
  } else {
    // round-1 fallback (ws >= 1.05 MB proven)
    double* c2  = (double*)ws;
    int* idx    = (int*)(ws + 4096);
    float* sums = (float*)(ws + 4096 + 524288);
    int* counts = (int*)(ws + 4096 + 524288 + 524288);
    hipMemsetAsync(sums, 0, (size_t)(KTOT * DIM + KTOT) * 4, stream);
    c2_kernel<<<KTOT, 64, 0, stream>>>(c, c2);
    assign_kernel_r1<<<NPTS / MP, 256, 0, stream>>>(x, c, c2, out, idx);
    sums_kernel<<<(KTOT / GB) * SLICES, 256, 0, stream>>>(x, idx, sums, counts);
    ema_kernel<<<KTOT, DIM, 0, stream>>>(c, sums, counts, outc);
  }
}